// Round 2
// baseline (1307.224 us; speedup 1.0000x reference)
//
#include <hip/hip_runtime.h>

typedef _Float16 f16;
typedef _Float16 f16x2 __attribute__((ext_vector_type(2)));
typedef _Float16 f16x4 __attribute__((ext_vector_type(4)));
typedef _Float16 f16x8 __attribute__((ext_vector_type(8)));
typedef float f32x4 __attribute__((ext_vector_type(4)));

#define DEVI static __device__ __forceinline__

constexpr int S_  = 2048;
constexpr int H_  = 16;
constexpr int BH_ = 32;   // B*H

DEVI float softplus_(float x){ return logf(1.0f + expf(x)); }
DEVI float exp2_(float x){ return __builtin_amdgcn_exp2f(x); }

DEVI f16x2 cvt2(float a, float b){
  return __builtin_bit_cast(f16x2, __builtin_amdgcn_cvt_pkrtz(a, b));
}

DEVI f16x8 pack8(float4 a, float4 b){
  f16x2 p0 = cvt2(a.x, a.y);
  f16x2 p1 = cvt2(a.z, a.w);
  f16x2 p2 = cvt2(b.x, b.y);
  f16x2 p3 = cvt2(b.z, b.w);
  f16x8 o;
  o[0]=p0[0]; o[1]=p0[1]; o[2]=p1[0]; o[3]=p1[1];
  o[4]=p2[0]; o[5]=p2[1]; o[6]=p3[0]; o[7]=p3[1];
  return o;
}

// ---------------------------------------------------------------------------
// GEMM: C[M=4096,N=1024] = A[M,K=1024] * W[N,K]^T   (torch Linear, NT form)
// mode 0: out f16 head-layout [B,H,S,64] (q or k)
// mode 2: out f32 head-layout (v)
// mode 3: A is f16 (y16), out f32 flat [M,N] (final projection)
// ---------------------------------------------------------------------------
__global__ __launch_bounds__(256) void gemm_k(
    const float* __restrict__ A32, const f16* __restrict__ A16,
    const float* __restrict__ W,
    f16* __restrict__ o16h, float* __restrict__ o32h, float* __restrict__ o32f,
    int mode)
{
  constexpr int K = 1024;
  int n0 = blockIdx.x*128, m0 = blockIdx.y*128;
  int tid = threadIdx.x, wave = tid>>6, lane = tid&63, lr_ = lane&15, lg = lane>>4;
  int wm = (wave&1)*64, wn = (wave>>1)*64;
  __shared__ __align__(16) f16 As[128][40];  // 32 k + 8 pad
  __shared__ __align__(16) f16 Ws[128][40];
  f32x4 acc[4][4];
  #pragma unroll
  for (int a=0;a<4;a++)
    #pragma unroll
    for (int b=0;b<4;b++) acc[a][b] = (f32x4){0.f,0.f,0.f,0.f};

  int row = tid>>2, c8 = (tid&3)*8;
  for (int kt=0; kt<K; kt+=32){
    #pragma unroll
    for (int p=0;p<2;p++){
      int rr = p*64 + row;
      if (mode==3){
        const f16* src = A16 + (size_t)(m0+rr)*K + kt + c8;
        *(f16x8*)&As[rr][c8] = *(const f16x8*)src;
      } else {
        const float* src = A32 + (size_t)(m0+rr)*K + kt + c8;
        float4 f0 = *(const float4*)src, f1 = *(const float4*)(src+4);
        *(f16x8*)&As[rr][c8] = pack8(f0,f1);
      }
      const float* wsrc = W + (size_t)(n0+rr)*K + kt + c8;
      float4 g0 = *(const float4*)wsrc, g1 = *(const float4*)(wsrc+4);
      *(f16x8*)&Ws[rr][c8] = pack8(g0,g1);
    }
    __syncthreads();
    f16x8 af[4], bf[4];
    #pragma unroll
    for (int mf=0;mf<4;mf++) af[mf] = *(const f16x8*)&As[wm+mf*16+lr_][lg*8];
    #pragma unroll
    for (int nf=0;nf<4;nf++) bf[nf] = *(const f16x8*)&Ws[wn+nf*16+lr_][lg*8];
    #pragma unroll
    for (int mf=0;mf<4;mf++)
      #pragma unroll
      for (int nf=0;nf<4;nf++)
        acc[mf][nf] = __builtin_amdgcn_mfma_f32_16x16x32_f16(af[mf], bf[nf], acc[mf][nf], 0,0,0);
    __syncthreads();
  }
  #pragma unroll
  for (int mf=0;mf<4;mf++)
    #pragma unroll
    for (int nf=0;nf<4;nf++)
      #pragma unroll
      for (int rg=0;rg<4;rg++){
        int grow = m0+wm+mf*16+lg*4+rg;     // row in [0,4096)
        int gcol = n0+wn+nf*16+lr_;         // col in [0,1024)
        float vv = acc[mf][nf][rg];
        if (mode==0){
          int b = grow>>11, s = grow&2047, hh = gcol>>6, d2 = gcol&63;
          o16h[(((size_t)(b*16+hh))*S_ + s)*64 + d2] = (f16)vv;
        } else if (mode==2){
          int b = grow>>11, s = grow&2047, hh = gcol>>6, d2 = gcol&63;
          o32h[(((size_t)(b*16+hh))*S_ + s)*64 + d2] = vv;
        } else {
          o32f[(size_t)grow*1024 + gcol] = vv;
        }
      }
}

// ---------------------------------------------------------------------------
// Per-row stats from f16 q/k (consistent with the MFMA inputs):
// bs = -|q|^2 * c2, ct = -|k|^2 * c2 (exp2-space), diag preconditioner.
// ---------------------------------------------------------------------------
__global__ __launch_bounds__(256) void stats_k(
    const f16* __restrict__ q16, const f16* __restrict__ k16,
    const float* __restrict__ bwp, const float* __restrict__ dsp, const float* __restrict__ rgp,
    float* __restrict__ bs, float* __restrict__ ct, float* __restrict__ dp)
{
  int g = blockIdx.x*256 + threadIdx.x;        // (bh,s) flat, 0..65535
  int h = (g>>11)&15;
  float bw = softplus_(bwp[0]) + 1e-6f;
  float c2 = 1.f/(2.f*bw*bw*0.6931471805599453f);
  const f16* qr = q16 + (size_t)g*64;
  const f16* kr = k16 + (size_t)g*64;
  float qsq=0.f, ksq=0.f, qk=0.f;
  #pragma unroll
  for (int c=0;c<8;c++){
    f16x8 qv = *(const f16x8*)(qr + c*8);
    f16x8 kv = *(const f16x8*)(kr + c*8);
    #pragma unroll
    for (int j=0;j<8;j++){
      float a = (float)qv[j], b = (float)kv[j];
      qsq += a*a; ksq += b*b; qk += a*b;
    }
  }
  bs[g] = -qsq*c2;
  ct[g] = -ksq*c2;
  float dist = fmaxf(qsq + ksq - 2.f*qk, 0.f);
  float kd = exp2_(-dist*c2);                       // kernel diagonal
  dp[g] = softplus_(kd)*dsp[h] + rgp[0];
}

// lr[h,s,p] = sum_r pos[s,r]*hp[h,r,p]
__global__ __launch_bounds__(256) void lr_k(
    const float* __restrict__ pos, const float* __restrict__ hpj, float* __restrict__ lr32)
{
  int g = blockIdx.x*256 + threadIdx.x;   // == (h*2048+s)*16+p
  int p = g&15, s = (g>>4)&2047, h = g>>15;
  float acc = 0.f;
  #pragma unroll
  for (int r=0;r<16;r++) acc += pos[s*16+r]*hpj[(h*16+r)*16+p];
  lr32[g] = acc;
}

// ---------------------------------------------------------------------------
// Fused apply: R = K @ alpha  (K recomputed on the fly via MFMA + exp2)
// mode 0: resid = v - R - lam*alpha      mode 1: y16[b,s,h*64+d] = R
// Swapped QK^T (A=k,B=q) so the S^T fragment feeds PV's A operand directly.
// ---------------------------------------------------------------------------
__global__ __launch_bounds__(256) void apply_k(
    const f16* __restrict__ q16, const f16* __restrict__ k16,
    const f16* __restrict__ alphaT,
    const float* __restrict__ bs, const float* __restrict__ ct,
    const float* __restrict__ v32, const float* __restrict__ alpha32,
    const float* __restrict__ bwp, const float* __restrict__ lmp,
    float* __restrict__ resid, f16* __restrict__ y16,
    int mode)
{
  // XCD-aware mapping: blocks with id%8==c share only 4 bh slices (2MB -> L2-fits)
  int id = blockIdx.x;                     // 0..1023
  int bh = ((id&7)<<2) | ((id>>3)&3);
  int sblk = id>>5;
  int s0 = sblk*64;

  float bw = softplus_(bwp[0]) + 1e-6f;
  float c2 = 1.f/(2.f*bw*bw*0.6931471805599453f);
  float acoef = 2.f*c2;

  int tid = threadIdx.x, wave = tid>>6, lane = tid&63, lr_ = lane&15, lg = lane>>4;
  int sw = s0 + wave*16;                   // this wave's 16 s-rows

  const f16* qrow = q16 + ((size_t)bh*S_ + sw + lr_)*64;
  f16x8 qf0 = *(const f16x8*)(qrow + lg*8);        // d 0..31 (per lane group)
  f16x8 qf1 = *(const f16x8*)(qrow + 32 + lg*8);   // d 32..63
  float bsv = bs[bh*S_ + sw + lr_];

  __shared__ __align__(16) f16 ks[64][72];   // k tile [t][d], +8 pad
  __shared__ __align__(16) f16 at[64][72];   // alpha^T tile [d][t], +8 pad
  __shared__ __align__(16) float cts[64];

  f32x4 racc[4];
  #pragma unroll
  for (int df=0;df<4;df++) racc[df] = (f32x4){0.f,0.f,0.f,0.f};

  int rr = tid>>2, cc = (tid&3)*16;
  const f16* kbase = k16   + ((size_t)bh*S_ + rr)*64 + cc;
  const f16* abase = alphaT + ((size_t)bh*64 + rr)*S_ + cc;
  const float* ctb = ct + (size_t)bh*S_;

  for (int t0=0; t0<S_; t0+=64){
    *(f16x8*)&ks[rr][cc]   = *(const f16x8*)(kbase + (size_t)t0*64);
    *(f16x8*)&ks[rr][cc+8] = *(const f16x8*)(kbase + (size_t)t0*64 + 8);
    *(f16x8*)&at[rr][cc]   = *(const f16x8*)(abase + t0);
    *(f16x8*)&at[rr][cc+8] = *(const f16x8*)(abase + t0 + 8);
    if (tid < 64) cts[tid] = ctb[t0 + tid];
    __syncthreads();
    #pragma unroll
    for (int tf=0; tf<4; tf++){
      f16x8 ka0 = *(const f16x8*)&ks[tf*16+lr_][lg*8];
      f16x8 ka1 = *(const f16x8*)&ks[tf*16+lr_][32+lg*8];
      f32x4 sacc = (f32x4){0.f,0.f,0.f,0.f};
      sacc = __builtin_amdgcn_mfma_f32_16x16x32_f16(ka0, qf0, sacc, 0,0,0);
      sacc = __builtin_amdgcn_mfma_f32_16x16x32_f16(ka1, qf1, sacc, 0,0,0);
      // lane holds S^T[t,s]: s = lr_, t = tf*16 + lg*4 + reg
      f32x4 ctv = *(const f32x4*)&cts[tf*16 + lg*4];
      float p0 = exp2_(fminf(fmaf(acoef, sacc[0], bsv + ctv[0]), 0.f));
      float p1 = exp2_(fminf(fmaf(acoef, sacc[1], bsv + ctv[1]), 0.f));
      float p2 = exp2_(fminf(fmaf(acoef, sacc[2], bsv + ctv[2]), 0.f));
      float p3 = exp2_(fminf(fmaf(acoef, sacc[3], bsv + ctv[3]), 0.f));
      f16x2 plo = cvt2(p0,p1);
      f16x2 phi = cvt2(p2,p3);
      f16x4 pa; pa[0]=plo[0]; pa[1]=plo[1]; pa[2]=phi[0]; pa[3]=phi[1];
      #pragma unroll
      for (int df=0; df<4; df++){
        f16x4 bfr = *(const f16x4*)&at[df*16+lr_][tf*16+lg*4];
        racc[df] = __builtin_amdgcn_mfma_f32_16x16x16f16(pa, bfr, racc[df], 0,0,0);
      }
    }
    __syncthreads();
  }

  if (mode==0){
    float lam = softplus_(lmp[0]) + 1e-6f;
    #pragma unroll
    for (int df=0; df<4; df++)
      #pragma unroll
      for (int rg=0; rg<4; rg++){
        int s = sw + lg*4 + rg, dd = df*16 + lr_;
        size_t gi = ((size_t)bh*S_ + s)*64 + dd;
        resid[gi] = v32[gi] - racc[df][rg] - lam*alpha32[gi];
      }
  } else {
    int b = bh>>4, h = bh&15;
    #pragma unroll
    for (int df=0; df<4; df++)
      #pragma unroll
      for (int rg=0; rg<4; rg++){
        int s = sw + lg*4 + rg, dd = df*16 + lr_;
        y16[((size_t)(b*S_+s))*1024 + h*64 + dd] = (f16)racc[df][rg];
      }
  }
}

// tbuf[bh,r,d] = sum_s lr[h,s,r]*resid[bh,s,d]   (full-S reduction, no atomics)
__global__ __launch_bounds__(256) void reduce_t_k(
    const float* __restrict__ lr32, const float* __restrict__ rsd, float* __restrict__ tbuf)
{
  int dblk = blockIdx.x, bh = blockIdx.y, h = bh&15;
  int tid = threadIdx.x, r = tid>>4, dc = tid&15;
  __shared__ __align__(16) float lr_s[128][20];
  __shared__ __align__(16) float rs[128][20];
  float acc = 0.f;
  int row = tid>>1, c8 = (tid&1)*8;
  for (int s0=0; s0<S_; s0+=128){
    const float* lp = lr32 + ((size_t)h*S_ + s0 + row)*16 + c8;
    const float* rp = rsd  + ((size_t)bh*S_ + s0 + row)*64 + dblk*16 + c8;
    float4 l0 = *(const float4*)lp, l1 = *(const float4*)(lp+4);
    float4 r0 = *(const float4*)rp, r1 = *(const float4*)(rp+4);
    *(float4*)&lr_s[row][c8]   = l0; *(float4*)&lr_s[row][c8+4] = l1;
    *(float4*)&rs[row][c8]     = r0; *(float4*)&rs[row][c8+4]   = r1;
    __syncthreads();
    #pragma unroll 8
    for (int ss=0; ss<128; ss++) acc += lr_s[ss][r]*rs[ss][dc];
    __syncthreads();
  }
  tbuf[((size_t)bh*16 + r)*64 + dblk*16 + dc] = acc;
}

// alpha = clip(alpha + dp*resid + lr@t), writes f32 alpha + transposed f16 copy
__global__ __launch_bounds__(256) void update_k(
    const float* __restrict__ rsd, const float* __restrict__ alpha_in, int alpha_zero,
    const float* __restrict__ lr32, const float* __restrict__ tbuf,
    const float* __restrict__ dpp,
    float* __restrict__ alpha_out, f16* __restrict__ alphaT)
{
  int sblk = blockIdx.x, bh = blockIdx.y, h = bh&15, s0 = sblk*64;
  int tid = threadIdx.x;
  __shared__ __align__(16) float tb_s[16][64];
  __shared__ __align__(16) float lr_s[64][20];
  __shared__ float dp_s[64];
  __shared__ __align__(16) f16 at_s[64][72];
  {
    float4 t4 = *(const float4*)(tbuf + (size_t)bh*1024 + tid*4);
    *(float4*)&((float*)tb_s)[tid*4] = t4;
    int row = tid>>2, c4 = (tid&3)*4;
    float4 l4 = *(const float4*)(lr32 + ((size_t)h*S_ + s0 + row)*16 + c4);
    *(float4*)&lr_s[row][c4] = l4;
    if (tid < 64) dp_s[tid] = dpp[(size_t)bh*S_ + s0 + tid];
  }
  __syncthreads();
  #pragma unroll
  for (int i=0;i<16;i++){
    int idx = i*256 + tid;
    int sl = idx>>6, dd = idx&63;
    size_t gi = ((size_t)bh*S_ + s0 + sl)*64 + dd;
    float rv = rsd[gi];
    float av = alpha_zero ? 0.f : alpha_in[gi];
    float acc = av + dp_s[sl]*rv;
    #pragma unroll
    for (int rr=0; rr<16; rr++) acc += lr_s[sl][rr]*tb_s[rr][dd];
    acc = fminf(fmaxf(acc, -10.f), 10.f);
    alpha_out[gi] = acc;
    at_s[dd][sl] = (f16)acc;
  }
  __syncthreads();
  int dd = tid>>2, c16 = (tid&3)*16;
  f16* dst = alphaT + ((size_t)bh*64 + dd)*S_ + s0 + c16;
  *(f16x8*)dst     = *(const f16x8*)&at_s[dd][c16];
  *(f16x8*)(dst+8) = *(const f16x8*)&at_s[dd][c16+8];
}

// ---------------------------------------------------------------------------
extern "C" void kernel_launch(void* const* d_in, const int* in_sizes, int n_in,
                              void* d_out, int out_size, void* d_ws, size_t ws_size,
                              hipStream_t stream)
{
  const float* x   = (const float*)d_in[0];
  const float* wq  = (const float*)d_in[1];
  const float* wk  = (const float*)d_in[2];
  const float* wv  = (const float*)d_in[3];
  const float* wo  = (const float*)d_in[4];
  const float* bwp = (const float*)d_in[5];
  const float* dsp = (const float*)d_in[6];
  const float* rgp = (const float*)d_in[7];
  const float* pos = (const float*)d_in[8];
  const float* hpj = (const float*)d_in[9];
  const float* lmp = (const float*)d_in[10];
  float* outp = (float*)d_out;

  char* base = (char*)d_ws;
  size_t off = 0;
  auto carve = [&](size_t bytes)->char* {
    char* p = base + off; off += (bytes + 255) & ~(size_t)255; return p;
  };
  f16*   q16    = (f16*)  carve((size_t)BH_*S_*64*2);   // 8 MB
  f16*   k16    = (f16*)  carve((size_t)BH_*S_*64*2);   // 8 MB
  float* v32    = (float*)carve((size_t)BH_*S_*64*4);   // 16 MB
  float* alpha  = (float*)carve((size_t)BH_*S_*64*4);   // 16 MB
  f16*   alphaT = (f16*)  carve((size_t)BH_*64*S_*2);   // 8 MB
  float* resid  = (float*)carve((size_t)BH_*S_*64*4);   // 16 MB
  f16*   y16    = (f16*)  carve((size_t)4096*1024*2);   // 8 MB
  float* bs     = (float*)carve((size_t)BH_*S_*4);
  float* ct     = (float*)carve((size_t)BH_*S_*4);
  float* dp     = (float*)carve((size_t)BH_*S_*4);
  float* lr32   = (float*)carve((size_t)H_*S_*16*4);    // 2 MB
  float* tbuf   = (float*)carve((size_t)BH_*16*64*4);   // 128 KB

  dim3 gg(8,32,1);
  // projections
  gemm_k<<<gg,256,0,stream>>>(x, nullptr, wq, q16, nullptr, nullptr, 0);
  gemm_k<<<gg,256,0,stream>>>(x, nullptr, wk, k16, nullptr, nullptr, 0);
  gemm_k<<<gg,256,0,stream>>>(x, nullptr, wv, nullptr, v32, nullptr, 2);
  stats_k<<<256,256,0,stream>>>(q16,k16,bwp,dsp,rgp,bs,ct,dp);
  lr_k<<<2048,256,0,stream>>>(pos,hpj,lr32);
  // iteration 1: alpha=0 -> residual = v (no heavy apply needed)
  reduce_t_k<<<dim3(4,32),256,0,stream>>>(lr32, v32, tbuf);
  update_k<<<dim3(32,32),256,0,stream>>>(v32, alpha, 1, lr32, tbuf, dp, alpha, alphaT);
  // iterations 2..8
  for (int it=1; it<8; ++it){
    apply_k<<<1024,256,0,stream>>>(q16,k16,alphaT,bs,ct,v32,alpha,bwp,lmp,resid,nullptr,0);
    reduce_t_k<<<dim3(4,32),256,0,stream>>>(lr32, resid, tbuf);
    update_k<<<dim3(32,32),256,0,stream>>>(resid, alpha, 0, lr32, tbuf, dp, alpha, alphaT);
  }
  // final: out = K @ alpha, then output projection
  apply_k<<<1024,256,0,stream>>>(q16,k16,alphaT,bs,ct,v32,alpha,bwp,lmp,resid,y16,1);
  gemm_k<<<gg,256,0,stream>>>(nullptr, y16, wo, nullptr, nullptr, outp, 3);
}

// Round 3
// 1051.058 us; speedup vs baseline: 1.2437x; 1.2437x over previous
//
#include <hip/hip_runtime.h>

typedef _Float16 f16;
typedef _Float16 f16x2 __attribute__((ext_vector_type(2)));
typedef _Float16 f16x4 __attribute__((ext_vector_type(4)));
typedef _Float16 f16x8 __attribute__((ext_vector_type(8)));
typedef float f32x4 __attribute__((ext_vector_type(4)));

#define DEVI static __device__ __forceinline__

constexpr int S_  = 2048;
constexpr int H_  = 16;
constexpr int BH_ = 32;   // B*H

DEVI float softplus_(float x){ return logf(1.0f + expf(x)); }
DEVI float exp2_(float x){ return __builtin_amdgcn_exp2f(x); }

DEVI f16x2 cvt2(float a, float b){
  return __builtin_bit_cast(f16x2, __builtin_amdgcn_cvt_pkrtz(a, b));
}

DEVI f16x8 pack8(float4 a, float4 b){
  f16x2 p0 = cvt2(a.x, a.y);
  f16x2 p1 = cvt2(a.z, a.w);
  f16x2 p2 = cvt2(b.x, b.y);
  f16x2 p3 = cvt2(b.z, b.w);
  f16x8 o;
  o[0]=p0[0]; o[1]=p0[1]; o[2]=p1[0]; o[3]=p1[1];
  o[4]=p2[0]; o[5]=p2[1]; o[6]=p3[0]; o[7]=p3[1];
  return o;
}

// ---------------------------------------------------------------------------
// GEMM: C[M=4096,N=1024] = A[M,K=1024] * W[N,K]^T   (torch Linear, NT form)
// mode 0: out f16 head-layout [B,H,S,64] (q or k)
// mode 2: out f32 head-layout (v)
// mode 3: A is f16 (y16), out f32 flat [M,N] (final projection)
// ---------------------------------------------------------------------------
__global__ __launch_bounds__(256) void gemm_k(
    const float* __restrict__ A32, const f16* __restrict__ A16,
    const float* __restrict__ W,
    f16* __restrict__ o16h, float* __restrict__ o32h, float* __restrict__ o32f,
    int mode)
{
  constexpr int K = 1024;
  int n0 = blockIdx.x*128, m0 = blockIdx.y*128;
  int tid = threadIdx.x, wave = tid>>6, lane = tid&63, lr_ = lane&15, lg = lane>>4;
  int wm = (wave&1)*64, wn = (wave>>1)*64;
  __shared__ __align__(16) f16 As[128][40];  // 32 k + 8 pad
  __shared__ __align__(16) f16 Ws[128][40];
  f32x4 acc[4][4];
  #pragma unroll
  for (int a=0;a<4;a++)
    #pragma unroll
    for (int b=0;b<4;b++) acc[a][b] = (f32x4){0.f,0.f,0.f,0.f};

  int row = tid>>2, c8 = (tid&3)*8;
  for (int kt=0; kt<K; kt+=32){
    #pragma unroll
    for (int p=0;p<2;p++){
      int rr = p*64 + row;
      if (mode==3){
        const f16* src = A16 + (size_t)(m0+rr)*K + kt + c8;
        *(f16x8*)&As[rr][c8] = *(const f16x8*)src;
      } else {
        const float* src = A32 + (size_t)(m0+rr)*K + kt + c8;
        float4 f0 = *(const float4*)src, f1 = *(const float4*)(src+4);
        *(f16x8*)&As[rr][c8] = pack8(f0,f1);
      }
      const float* wsrc = W + (size_t)(n0+rr)*K + kt + c8;
      float4 g0 = *(const float4*)wsrc, g1 = *(const float4*)(wsrc+4);
      *(f16x8*)&Ws[rr][c8] = pack8(g0,g1);
    }
    __syncthreads();
    f16x8 af[4], bf[4];
    #pragma unroll
    for (int mf=0;mf<4;mf++) af[mf] = *(const f16x8*)&As[wm+mf*16+lr_][lg*8];
    #pragma unroll
    for (int nf=0;nf<4;nf++) bf[nf] = *(const f16x8*)&Ws[wn+nf*16+lr_][lg*8];
    #pragma unroll
    for (int mf=0;mf<4;mf++)
      #pragma unroll
      for (int nf=0;nf<4;nf++)
        acc[mf][nf] = __builtin_amdgcn_mfma_f32_16x16x32_f16(af[mf], bf[nf], acc[mf][nf], 0,0,0);
    __syncthreads();
  }
  #pragma unroll
  for (int mf=0;mf<4;mf++)
    #pragma unroll
    for (int nf=0;nf<4;nf++)
      #pragma unroll
      for (int rg=0;rg<4;rg++){
        int grow = m0+wm+mf*16+lg*4+rg;     // row in [0,4096)
        int gcol = n0+wn+nf*16+lr_;         // col in [0,1024)
        float vv = acc[mf][nf][rg];
        if (mode==0){
          int b = grow>>11, s = grow&2047, hh = gcol>>6, d2 = gcol&63;
          o16h[(((size_t)(b*16+hh))*S_ + s)*64 + d2] = (f16)vv;
        } else if (mode==2){
          int b = grow>>11, s = grow&2047, hh = gcol>>6, d2 = gcol&63;
          o32h[(((size_t)(b*16+hh))*S_ + s)*64 + d2] = vv;
        } else {
          o32f[(size_t)grow*1024 + gcol] = vv;
        }
      }
}

// ---------------------------------------------------------------------------
// Per-row stats from f16 q/k (consistent with the MFMA inputs)
// ---------------------------------------------------------------------------
__global__ __launch_bounds__(256) void stats_k(
    const f16* __restrict__ q16, const f16* __restrict__ k16,
    const float* __restrict__ bwp, const float* __restrict__ dsp, const float* __restrict__ rgp,
    float* __restrict__ bs, float* __restrict__ ct, float* __restrict__ dp)
{
  int g = blockIdx.x*256 + threadIdx.x;        // (bh,s) flat, 0..65535
  int h = (g>>11)&15;
  float bw = softplus_(bwp[0]) + 1e-6f;
  float c2 = 1.f/(2.f*bw*bw*0.6931471805599453f);
  const f16* qr = q16 + (size_t)g*64;
  const f16* kr = k16 + (size_t)g*64;
  float qsq=0.f, ksq=0.f, qk=0.f;
  #pragma unroll
  for (int c=0;c<8;c++){
    f16x8 qv = *(const f16x8*)(qr + c*8);
    f16x8 kv = *(const f16x8*)(kr + c*8);
    #pragma unroll
    for (int j=0;j<8;j++){
      float a = (float)qv[j], b = (float)kv[j];
      qsq += a*a; ksq += b*b; qk += a*b;
    }
  }
  bs[g] = -qsq*c2;
  ct[g] = -ksq*c2;
  float dist = fmaxf(qsq + ksq - 2.f*qk, 0.f);
  float kd = exp2_(-dist*c2);
  dp[g] = softplus_(kd)*dsp[h] + rgp[0];
}

// lr[h,s,p] = sum_r pos[s,r]*hp[h,r,p]
__global__ __launch_bounds__(256) void lr_k(
    const float* __restrict__ pos, const float* __restrict__ hpj, float* __restrict__ lr32)
{
  int g = blockIdx.x*256 + threadIdx.x;   // == (h*2048+s)*16+p
  int p = g&15, s = (g>>4)&2047, h = g>>15;
  float acc = 0.f;
  #pragma unroll
  for (int r=0;r<16;r++) acc += pos[s*16+r]*hpj[(h*16+r)*16+p];
  lr32[g] = acc;
}

// ---------------------------------------------------------------------------
// Fused apply v2: R = K @ alpha, 32 s-rows per wave (2 s-blocks), 128-s block,
// register-prefetch pipelined staging.
// mode 0: resid = v - R - lam*alpha      mode 1: y16[b,s,h*64+d] = R
// ---------------------------------------------------------------------------
__global__ __launch_bounds__(256) void apply_k(
    const f16* __restrict__ q16, const f16* __restrict__ k16,
    const f16* __restrict__ alphaT,
    const float* __restrict__ bs, const float* __restrict__ ct,
    const float* __restrict__ v32, const float* __restrict__ alpha32,
    const float* __restrict__ bwp, const float* __restrict__ lmp,
    float* __restrict__ resid, f16* __restrict__ y16,
    int mode)
{
  // grid = 512: XCD-aware: 4 bh per XCD -> k16+alphaT slices (2MB) L2-resident
  int id = blockIdx.x;
  int bh = ((id&7)<<2) | ((id>>3)&3);
  int s0 = (id>>5)*128;

  float bw = softplus_(bwp[0]) + 1e-6f;
  float c2 = 1.f/(2.f*bw*bw*0.6931471805599453f);
  float acoef = 2.f*c2;

  int tid = threadIdx.x, wave = tid>>6, lane = tid&63, lr_ = lane&15, lg = lane>>4;
  int sw = s0 + wave*32;                   // this wave's 32 s-rows

  const f16* qrowA = q16 + ((size_t)bh*S_ + sw + lr_)*64;
  const f16* qrowB = qrowA + 16*64;
  f16x8 qa0 = *(const f16x8*)(qrowA + lg*8);
  f16x8 qa1 = *(const f16x8*)(qrowA + 32 + lg*8);
  f16x8 qb0 = *(const f16x8*)(qrowB + lg*8);
  f16x8 qb1 = *(const f16x8*)(qrowB + 32 + lg*8);
  float bsva = bs[bh*S_ + sw + lr_];
  float bsvb = bs[bh*S_ + sw + 16 + lr_];

  __shared__ __align__(16) f16 ks[64][72];   // k tile [t][d], +8 pad
  __shared__ __align__(16) f16 at[64][72];   // alpha^T tile [d][t], +8 pad
  __shared__ float cts[64];

  f32x4 ra[4], rb[4];
  #pragma unroll
  for (int df=0;df<4;df++){ ra[df] = (f32x4){0.f,0.f,0.f,0.f}; rb[df] = (f32x4){0.f,0.f,0.f,0.f}; }

  // staging ownership: thread owns chunks c0=2*tid, c0+1 (16B each), 512 chunks/tile
  int c0 = tid*2;
  int srow = c0>>3, scol = (c0&7)*8;       // tile-local row / f16 col
  const f16* kg = k16    + ((size_t)bh*S_ + srow)*64 + scol;   // + t0*64
  const f16* ag = alphaT + ((size_t)bh*64 + srow)*S_ + scol;   // + t0
  const float* ctb = ct + (size_t)bh*S_;
  int lct = tid&63;

  f16x8 kv0,kv1,av0,av1; float ctp;
  auto LOADT = [&](int t0){
    kv0 = *(const f16x8*)(kg + (size_t)t0*64);
    kv1 = *(const f16x8*)(kg + (size_t)t0*64 + 8);
    av0 = *(const f16x8*)(ag + t0);
    av1 = *(const f16x8*)(ag + t0 + 8);
    ctp = ctb[t0 + lct];
  };
  auto STORET = [&](){
    *(f16x8*)&ks[srow][scol]   = kv0;
    *(f16x8*)&ks[srow][scol+8] = kv1;
    *(f16x8*)&at[srow][scol]   = av0;
    *(f16x8*)&at[srow][scol+8] = av1;
    cts[lct] = ctp;                         // all waves write identical value
  };

  LOADT(0);
  STORET();
  __syncthreads();

  for (int t0=0; t0<S_; t0+=64){
    bool notlast = (t0+64 < S_);
    if (notlast) LOADT(t0+64);
    #pragma unroll
    for (int tf=0; tf<4; tf++){
      f16x8 ka0 = *(const f16x8*)&ks[tf*16+lr_][lg*8];
      f16x8 ka1 = *(const f16x8*)&ks[tf*16+lr_][32+lg*8];
      f32x4 sa = (f32x4){0.f,0.f,0.f,0.f};
      f32x4 sb = (f32x4){0.f,0.f,0.f,0.f};
      sa = __builtin_amdgcn_mfma_f32_16x16x32_f16(ka0, qa0, sa, 0,0,0);
      sa = __builtin_amdgcn_mfma_f32_16x16x32_f16(ka1, qa1, sa, 0,0,0);
      sb = __builtin_amdgcn_mfma_f32_16x16x32_f16(ka0, qb0, sb, 0,0,0);
      sb = __builtin_amdgcn_mfma_f32_16x16x32_f16(ka1, qb1, sb, 0,0,0);
      f32x4 ctv = *(const f32x4*)&cts[tf*16 + lg*4];
      float pa0 = exp2_(fminf(fmaf(acoef, sa[0], bsva + ctv[0]), 0.f));
      float pa1 = exp2_(fminf(fmaf(acoef, sa[1], bsva + ctv[1]), 0.f));
      float pa2 = exp2_(fminf(fmaf(acoef, sa[2], bsva + ctv[2]), 0.f));
      float pa3 = exp2_(fminf(fmaf(acoef, sa[3], bsva + ctv[3]), 0.f));
      float pb0 = exp2_(fminf(fmaf(acoef, sb[0], bsvb + ctv[0]), 0.f));
      float pb1 = exp2_(fminf(fmaf(acoef, sb[1], bsvb + ctv[1]), 0.f));
      float pb2 = exp2_(fminf(fmaf(acoef, sb[2], bsvb + ctv[2]), 0.f));
      float pb3 = exp2_(fminf(fmaf(acoef, sb[3], bsvb + ctv[3]), 0.f));
      f16x2 alo = cvt2(pa0,pa1), ahi = cvt2(pa2,pa3);
      f16x2 blo = cvt2(pb0,pb1), bhi = cvt2(pb2,pb3);
      f16x4 paf; paf[0]=alo[0]; paf[1]=alo[1]; paf[2]=ahi[0]; paf[3]=ahi[1];
      f16x4 pbf; pbf[0]=blo[0]; pbf[1]=blo[1]; pbf[2]=bhi[0]; pbf[3]=bhi[1];
      #pragma unroll
      for (int df=0; df<4; df++){
        f16x4 bfr = *(const f16x4*)&at[df*16+lr_][tf*16+lg*4];
        ra[df] = __builtin_amdgcn_mfma_f32_16x16x16f16(paf, bfr, ra[df], 0,0,0);
        rb[df] = __builtin_amdgcn_mfma_f32_16x16x16f16(pbf, bfr, rb[df], 0,0,0);
      }
    }
    if (notlast){
      __syncthreads();      // all waves done reading current tile
      STORET();             // compiler inserts vmcnt wait
      __syncthreads();
    }
  }

  if (mode==0){
    float lam = softplus_(lmp[0]) + 1e-6f;
    #pragma unroll
    for (int df=0; df<4; df++)
      #pragma unroll
      for (int rg=0; rg<4; rg++){
        int dd = df*16 + lr_;
        int s_a = sw + lg*4 + rg;
        size_t ga = ((size_t)bh*S_ + s_a)*64 + dd;
        resid[ga] = v32[ga] - ra[df][rg] - lam*alpha32[ga];
        size_t gb = ga + (size_t)16*64;
        resid[gb] = v32[gb] - rb[df][rg] - lam*alpha32[gb];
      }
  } else {
    int b = bh>>4, h = bh&15;
    #pragma unroll
    for (int df=0; df<4; df++)
      #pragma unroll
      for (int rg=0; rg<4; rg++){
        int dd = df*16 + lr_;
        int s_a = sw + lg*4 + rg;
        y16[((size_t)(b*S_+s_a))*1024 + h*64 + dd]      = (f16)ra[df][rg];
        y16[((size_t)(b*S_+s_a+16))*1024 + h*64 + dd]   = (f16)rb[df][rg];
      }
  }
}

// rbuf[sc,bh,r,d] = sum_{s in chunk sc} lr[h,s,r]*resid[bh,s,d]  (8 chunks of 256)
__global__ __launch_bounds__(256) void reduce_t_k(
    const float* __restrict__ lr32, const float* __restrict__ rsd, float* __restrict__ rbuf)
{
  int dblk = blockIdx.x, bh = blockIdx.y, sc = blockIdx.z, h = bh&15;
  int tid = threadIdx.x, r = tid>>4, dc = tid&15;
  __shared__ __align__(16) float lr_s[128][20];
  __shared__ __align__(16) float rs[128][20];
  float acc = 0.f;
  int row = tid>>1, c8 = (tid&1)*8;
  for (int s0=sc*256; s0<sc*256+256; s0+=128){
    const float* lp = lr32 + ((size_t)h*S_ + s0 + row)*16 + c8;
    const float* rp = rsd  + ((size_t)bh*S_ + s0 + row)*64 + dblk*16 + c8;
    float4 l0 = *(const float4*)lp, l1 = *(const float4*)(lp+4);
    float4 r0 = *(const float4*)rp, r1 = *(const float4*)(rp+4);
    *(float4*)&lr_s[row][c8]   = l0; *(float4*)&lr_s[row][c8+4] = l1;
    *(float4*)&rs[row][c8]     = r0; *(float4*)&rs[row][c8+4]   = r1;
    __syncthreads();
    #pragma unroll 8
    for (int ss=0; ss<128; ss++) acc += lr_s[ss][r]*rs[ss][dc];
    __syncthreads();
  }
  rbuf[((size_t)(sc*32+bh)*16 + r)*64 + dblk*16 + dc] = acc;
}

// alpha = clip(alpha + dp*resid + lr@t), t = sum of 8 rbuf partials
__global__ __launch_bounds__(256) void update_k(
    const float* __restrict__ rsd, const float* __restrict__ alpha_in, int alpha_zero,
    const float* __restrict__ lr32, const float* __restrict__ rbuf,
    const float* __restrict__ dpp,
    float* __restrict__ alpha_out, f16* __restrict__ alphaT)
{
  int sblk = blockIdx.x, bh = blockIdx.y, h = bh&15, s0 = sblk*64;
  int tid = threadIdx.x;
  __shared__ __align__(16) float tb_s[16][64];
  __shared__ __align__(16) float lr_s[64][20];
  __shared__ float dp_s[64];
  __shared__ __align__(16) f16 at_s[64][72];
  {
    float4 t4 = {0.f,0.f,0.f,0.f};
    #pragma unroll
    for (int sc=0; sc<8; sc++){
      float4 p4 = *(const float4*)(rbuf + (size_t)(sc*32+bh)*1024 + tid*4);
      t4.x += p4.x; t4.y += p4.y; t4.z += p4.z; t4.w += p4.w;
    }
    *(float4*)&((float*)tb_s)[tid*4] = t4;
    int row = tid>>2, c4 = (tid&3)*4;
    float4 l4 = *(const float4*)(lr32 + ((size_t)h*S_ + s0 + row)*16 + c4);
    *(float4*)&lr_s[row][c4] = l4;
    if (tid < 64) dp_s[tid] = dpp[(size_t)bh*S_ + s0 + tid];
  }
  __syncthreads();
  #pragma unroll
  for (int i=0;i<16;i++){
    int idx = i*256 + tid;
    int sl = idx>>6, dd = idx&63;
    size_t gi = ((size_t)bh*S_ + s0 + sl)*64 + dd;
    float rv = rsd[gi];
    float av = alpha_zero ? 0.f : alpha_in[gi];
    float acc = av + dp_s[sl]*rv;
    #pragma unroll
    for (int rr=0; rr<16; rr++) acc += lr_s[sl][rr]*tb_s[rr][dd];
    acc = fminf(fmaxf(acc, -10.f), 10.f);
    alpha_out[gi] = acc;
    at_s[dd][sl] = (f16)acc;
  }
  __syncthreads();
  int dd = tid>>2, c16 = (tid&3)*16;
  f16* dst = alphaT + ((size_t)bh*64 + dd)*S_ + s0 + c16;
  *(f16x8*)dst     = *(const f16x8*)&at_s[dd][c16];
  *(f16x8*)(dst+8) = *(const f16x8*)&at_s[dd][c16+8];
}

// ---------------------------------------------------------------------------
extern "C" void kernel_launch(void* const* d_in, const int* in_sizes, int n_in,
                              void* d_out, int out_size, void* d_ws, size_t ws_size,
                              hipStream_t stream)
{
  const float* x   = (const float*)d_in[0];
  const float* wq  = (const float*)d_in[1];
  const float* wk  = (const float*)d_in[2];
  const float* wv  = (const float*)d_in[3];
  const float* wo  = (const float*)d_in[4];
  const float* bwp = (const float*)d_in[5];
  const float* dsp = (const float*)d_in[6];
  const float* rgp = (const float*)d_in[7];
  const float* pos = (const float*)d_in[8];
  const float* hpj = (const float*)d_in[9];
  const float* lmp = (const float*)d_in[10];
  float* outp = (float*)d_out;

  char* base = (char*)d_ws;
  size_t off = 0;
  auto carve = [&](size_t bytes)->char* {
    char* p = base + off; off += (bytes + 255) & ~(size_t)255; return p;
  };
  f16*   q16    = (f16*)  carve((size_t)BH_*S_*64*2);   // 8 MB
  f16*   k16    = (f16*)  carve((size_t)BH_*S_*64*2);   // 8 MB
  float* v32    = (float*)carve((size_t)BH_*S_*64*4);   // 16 MB
  float* alpha  = (float*)carve((size_t)BH_*S_*64*4);   // 16 MB
  f16*   alphaT = (f16*)  carve((size_t)BH_*64*S_*2);   // 8 MB
  float* resid  = (float*)carve((size_t)BH_*S_*64*4);   // 16 MB
  f16*   y16    = (f16*)  carve((size_t)4096*1024*2);   // 8 MB
  float* bs     = (float*)carve((size_t)BH_*S_*4);
  float* ct     = (float*)carve((size_t)BH_*S_*4);
  float* dp     = (float*)carve((size_t)BH_*S_*4);
  float* lr32   = (float*)carve((size_t)H_*S_*16*4);    // 2 MB
  float* rbuf   = (float*)carve((size_t)8*BH_*16*64*4); // 2 MB

  dim3 gg(8,32,1);
  gemm_k<<<gg,256,0,stream>>>(x, nullptr, wq, q16, nullptr, nullptr, 0);
  gemm_k<<<gg,256,0,stream>>>(x, nullptr, wk, k16, nullptr, nullptr, 0);
  gemm_k<<<gg,256,0,stream>>>(x, nullptr, wv, nullptr, v32, nullptr, 2);
  stats_k<<<256,256,0,stream>>>(q16,k16,bwp,dsp,rgp,bs,ct,dp);
  lr_k<<<2048,256,0,stream>>>(pos,hpj,lr32);
  // iteration 1: alpha=0 -> residual = v
  reduce_t_k<<<dim3(4,32,8),256,0,stream>>>(lr32, v32, rbuf);
  update_k<<<dim3(32,32),256,0,stream>>>(v32, alpha, 1, lr32, rbuf, dp, alpha, alphaT);
  // iterations 2..8
  for (int it=1; it<8; ++it){
    apply_k<<<512,256,0,stream>>>(q16,k16,alphaT,bs,ct,v32,alpha,bwp,lmp,resid,nullptr,0);
    reduce_t_k<<<dim3(4,32,8),256,0,stream>>>(lr32, resid, rbuf);
    update_k<<<dim3(32,32),256,0,stream>>>(resid, alpha, 0, lr32, rbuf, dp, alpha, alphaT);
  }
  // final: out = K @ alpha, then output projection
  apply_k<<<512,256,0,stream>>>(q16,k16,alphaT,bs,ct,v32,alpha,bwp,lmp,resid,y16,1);
  gemm_k<<<gg,256,0,stream>>>(nullptr, y16, wo, nullptr, nullptr, outp, 3);
}

// Round 5
// 1012.232 us; speedup vs baseline: 1.2914x; 1.0384x over previous
//
#include <hip/hip_runtime.h>

typedef _Float16 f16;
typedef _Float16 f16x2 __attribute__((ext_vector_type(2)));
typedef _Float16 f16x4 __attribute__((ext_vector_type(4)));
typedef _Float16 f16x8 __attribute__((ext_vector_type(8)));
typedef float f32x4 __attribute__((ext_vector_type(4)));

#define DEVI static __device__ __forceinline__

constexpr int S_  = 2048;
constexpr int H_  = 16;
constexpr int BH_ = 32;   // B*H

DEVI float softplus_(float x){ return logf(1.0f + expf(x)); }
DEVI float exp2_(float x){ return __builtin_amdgcn_exp2f(x); }

DEVI f16x2 cvt2(float a, float b){
  return __builtin_bit_cast(f16x2, __builtin_amdgcn_cvt_pkrtz(a, b));
}

DEVI f16x8 pack8(float4 a, float4 b){
  f16x2 p0 = cvt2(a.x, a.y);
  f16x2 p1 = cvt2(a.z, a.w);
  f16x2 p2 = cvt2(b.x, b.y);
  f16x2 p3 = cvt2(b.z, b.w);
  f16x8 o;
  o[0]=p0[0]; o[1]=p0[1]; o[2]=p1[0]; o[3]=p1[1];
  o[4]=p2[0]; o[5]=p2[1]; o[6]=p3[0]; o[7]=p3[1];
  return o;
}

DEVI void g2l16(const f16* g, f16* l){
  __builtin_amdgcn_global_load_lds(
      (const __attribute__((address_space(1))) void*)(g),
      (__attribute__((address_space(3))) void*)(l), 16, 0, 0);
}

// f32 -> f16 convert, 8 elems/thread
__global__ __launch_bounds__(256) void cvt_k(
    const float* __restrict__ src, f16* __restrict__ dst, int n8)
{
  int i = blockIdx.x*256 + threadIdx.x;
  if (i < n8){
    const float* s = src + (size_t)i*8;
    float4 a = *(const float4*)s, b = *(const float4*)(s+4);
    *(f16x8*)(dst + (size_t)i*8) = pack8(a,b);
  }
}

// ---------------------------------------------------------------------------
// f16 GEMM, m97-style: C[M,N] = A[M,1024] * W[N,1024]^T
// 128x128 tile, BK=32, global_load_lds width-16, linear LDS.
// mode 0: N=3072 fused QKV -> q16/k16 f16 head-layout, v32 f32 head-layout
// mode 1: N=1024 -> o32f flat f32 [M,N]
// ---------------------------------------------------------------------------
__global__ __launch_bounds__(256) void gemm16_k(
    const f16* __restrict__ A, const f16* __restrict__ W,
    f16* __restrict__ q16, f16* __restrict__ k16, float* __restrict__ v32,
    float* __restrict__ o32f, int mode)
{
  constexpr int K = 1024;
  int n0 = blockIdx.x*128, m0 = blockIdx.y*128;
  int tid = threadIdx.x, wave = tid>>6, lane = tid&63, lr_ = lane&15, lg = lane>>4;
  int wm = (wave&1)*64, wn = (wave>>1)*64;
  __shared__ __align__(16) f16 As[128*32];
  __shared__ __align__(16) f16 Ws[128*32];
  f32x4 acc[4][4];
  #pragma unroll
  for (int a=0;a<4;a++)
    #pragma unroll
    for (int b=0;b<4;b++) acc[a][b] = (f32x4){0.f,0.f,0.f,0.f};

  // staging: 512 16B-chunks per tile; thread owns chunks tid, tid+256
  int r1 = tid>>2,        o1 = (tid&3)*8;         // chunk tid
  int r2 = (tid+256)>>2,  o2 = ((tid+256)&3)*8;   // chunk tid+256
  const f16* a1 = A + (size_t)(m0+r1)*K + o1;
  const f16* a2 = A + (size_t)(m0+r2)*K + o2;
  const f16* w1 = W + (size_t)(n0+r1)*K + o1;
  const f16* w2 = W + (size_t)(n0+r2)*K + o2;
  f16* la1 = &As[tid*8];  f16* la2 = &As[(tid+256)*8];
  f16* lw1 = &Ws[tid*8];  f16* lw2 = &Ws[(tid+256)*8];

  for (int kt=0; kt<K; kt+=32){
    g2l16(a1 + kt, la1);
    g2l16(a2 + kt, la2);
    g2l16(w1 + kt, lw1);
    g2l16(w2 + kt, lw2);
    __syncthreads();
    f16x8 af[4], bf[4];
    #pragma unroll
    for (int mf=0;mf<4;mf++) af[mf] = *(const f16x8*)&As[(wm+mf*16+lr_)*32 + lg*8];
    #pragma unroll
    for (int nf=0;nf<4;nf++) bf[nf] = *(const f16x8*)&Ws[(wn+nf*16+lr_)*32 + lg*8];
    #pragma unroll
    for (int mf=0;mf<4;mf++)
      #pragma unroll
      for (int nf=0;nf<4;nf++)
        acc[mf][nf] = __builtin_amdgcn_mfma_f32_16x16x32_f16(af[mf], bf[nf], acc[mf][nf], 0,0,0);
    __syncthreads();
  }
  #pragma unroll
  for (int mf=0;mf<4;mf++)
    #pragma unroll
    for (int nf=0;nf<4;nf++)
      #pragma unroll
      for (int rg=0;rg<4;rg++){
        int grow = m0+wm+mf*16+lg*4+rg;
        int gcol = n0+wn+nf*16+lr_;
        float vv = acc[mf][nf][rg];
        if (mode==0){
          int mat = gcol>>10, col = gcol&1023;
          int b = grow>>11, s = grow&2047, hh = col>>6, d2 = col&63;
          size_t gi = (((size_t)(b*16+hh))*S_ + s)*64 + d2;
          if (mat==0)      q16[gi] = (f16)vv;
          else if (mat==1) k16[gi] = (f16)vv;
          else             v32[gi] = vv;
        } else {
          o32f[(size_t)grow*1024 + gcol] = vv;
        }
      }
}

// ---------------------------------------------------------------------------
// Per-row stats from f16 q/k
// ---------------------------------------------------------------------------
__global__ __launch_bounds__(256) void stats_k(
    const f16* __restrict__ q16, const f16* __restrict__ k16,
    const float* __restrict__ bwp, const float* __restrict__ dsp, const float* __restrict__ rgp,
    float* __restrict__ bs, float* __restrict__ ct, float* __restrict__ dp)
{
  int g = blockIdx.x*256 + threadIdx.x;        // (bh,s) flat
  int h = (g>>11)&15;
  float bw = softplus_(bwp[0]) + 1e-6f;
  float c2 = 1.f/(2.f*bw*bw*0.6931471805599453f);
  const f16* qr = q16 + (size_t)g*64;
  const f16* kr = k16 + (size_t)g*64;
  float qsq=0.f, ksq=0.f, qk=0.f;
  #pragma unroll
  for (int c=0;c<8;c++){
    f16x8 qv = *(const f16x8*)(qr + c*8);
    f16x8 kv = *(const f16x8*)(kr + c*8);
    #pragma unroll
    for (int j=0;j<8;j++){
      float a = (float)qv[j], b = (float)kv[j];
      qsq += a*a; ksq += b*b; qk += a*b;
    }
  }
  bs[g] = -qsq*c2;
  ct[g] = -ksq*c2;
  float dist = fmaxf(qsq + ksq - 2.f*qk, 0.f);
  float kd = exp2_(-dist*c2);
  dp[g] = softplus_(kd)*dsp[h] + rgp[0];
}

// lr[h,s,p] = sum_r pos[s,r]*hp[h,r,p]
__global__ __launch_bounds__(256) void lr_k(
    const float* __restrict__ pos, const float* __restrict__ hpj, float* __restrict__ lr32)
{
  int g = blockIdx.x*256 + threadIdx.x;
  int p = g&15, s = (g>>4)&2047, h = g>>15;
  float acc = 0.f;
  #pragma unroll
  for (int r=0;r<16;r++) acc += pos[s*16+r]*hpj[(h*16+r)*16+p];
  lr32[g] = acc;
}

// ---------------------------------------------------------------------------
// Fused apply v3: R = K @ alpha, 64 s-rows per wave, 256-s block, grid 256.
// mode 0: resid = v - R - lam*alpha      mode 1: y16[b,s,h*64+d] = R
// ---------------------------------------------------------------------------
__global__ __launch_bounds__(256,1) void apply_k(
    const f16* __restrict__ q16, const f16* __restrict__ k16,
    const f16* __restrict__ alphaT,
    const float* __restrict__ bs, const float* __restrict__ ct,
    const float* __restrict__ v32, const float* __restrict__ alpha32,
    const float* __restrict__ bwp, const float* __restrict__ lmp,
    float* __restrict__ resid, f16* __restrict__ y16,
    int mode)
{
  // grid = 256: 4 bh per XCD -> k16+alphaT slices (2MB) L2-resident
  int id = blockIdx.x;
  int bh = ((id&7)<<2) | ((id>>3)&3);
  int s0 = (id>>5)*256;

  float bw = softplus_(bwp[0]) + 1e-6f;
  float c2 = 1.f/(2.f*bw*bw*0.6931471805599453f);
  float acoef = 2.f*c2;

  int tid = threadIdx.x, wave = tid>>6, lane = tid&63, lr_ = lane&15, lg = lane>>4;
  int sw = s0 + wave*64;                   // this wave's 64 s-rows (4 x 16)

  f16x8 q0[4], q1[4]; float bsv[4];
  #pragma unroll
  for (int sub=0; sub<4; sub++){
    const f16* qr = q16 + ((size_t)bh*S_ + sw + sub*16 + lr_)*64;
    q0[sub] = *(const f16x8*)(qr + lg*8);
    q1[sub] = *(const f16x8*)(qr + 32 + lg*8);
    bsv[sub] = bs[bh*S_ + sw + sub*16 + lr_];
  }

  __shared__ __align__(16) f16 ks[64][72];
  __shared__ __align__(16) f16 at[64][72];
  __shared__ float cts[64];

  f32x4 racc[4][4];
  #pragma unroll
  for (int sub=0;sub<4;sub++)
    #pragma unroll
    for (int df=0;df<4;df++) racc[sub][df] = (f32x4){0.f,0.f,0.f,0.f};

  int c0 = tid*2;
  int srow = c0>>3, scol = (c0&7)*8;
  const f16* kg = k16    + ((size_t)bh*S_ + srow)*64 + scol;
  const f16* ag = alphaT + ((size_t)bh*64 + srow)*S_ + scol;
  const float* ctb = ct + (size_t)bh*S_;
  int lct = tid&63;

  f16x8 kv0,kv1,av0,av1; float ctp;
  auto LOADT = [&](int t0){
    kv0 = *(const f16x8*)(kg + (size_t)t0*64);
    kv1 = *(const f16x8*)(kg + (size_t)t0*64 + 8);
    av0 = *(const f16x8*)(ag + t0);
    av1 = *(const f16x8*)(ag + t0 + 8);
    ctp = ctb[t0 + lct];
  };
  auto STORET = [&](){
    *(f16x8*)&ks[srow][scol]   = kv0;
    *(f16x8*)&ks[srow][scol+8] = kv1;
    *(f16x8*)&at[srow][scol]   = av0;
    *(f16x8*)&at[srow][scol+8] = av1;
    cts[lct] = ctp;
  };

  LOADT(0);
  STORET();
  __syncthreads();

  for (int t0=0; t0<S_; t0+=64){
    bool notlast = (t0+64 < S_);
    if (notlast) LOADT(t0+64);
    #pragma unroll
    for (int tf=0; tf<4; tf++){
      f16x8 ka0 = *(const f16x8*)&ks[tf*16+lr_][lg*8];
      f16x8 ka1 = *(const f16x8*)&ks[tf*16+lr_][32+lg*8];
      f32x4 sacc[4];
      #pragma unroll
      for (int sub=0; sub<4; sub++){
        sacc[sub] = (f32x4){0.f,0.f,0.f,0.f};
        sacc[sub] = __builtin_amdgcn_mfma_f32_16x16x32_f16(ka0, q0[sub], sacc[sub], 0,0,0);
        sacc[sub] = __builtin_amdgcn_mfma_f32_16x16x32_f16(ka1, q1[sub], sacc[sub], 0,0,0);
      }
      f32x4 ctv = *(const f32x4*)&cts[tf*16 + lg*4];
      f16x4 paf[4];
      #pragma unroll
      for (int sub=0; sub<4; sub++){
        float p0 = exp2_(fminf(fmaf(acoef, sacc[sub][0], bsv[sub] + ctv[0]), 0.f));
        float p1 = exp2_(fminf(fmaf(acoef, sacc[sub][1], bsv[sub] + ctv[1]), 0.f));
        float p2 = exp2_(fminf(fmaf(acoef, sacc[sub][2], bsv[sub] + ctv[2]), 0.f));
        float p3 = exp2_(fminf(fmaf(acoef, sacc[sub][3], bsv[sub] + ctv[3]), 0.f));
        f16x2 lo = cvt2(p0,p1), hi = cvt2(p2,p3);
        paf[sub][0]=lo[0]; paf[sub][1]=lo[1]; paf[sub][2]=hi[0]; paf[sub][3]=hi[1];
      }
      #pragma unroll
      for (int df=0; df<4; df++){
        f16x4 bfr = *(const f16x4*)&at[df*16+lr_][tf*16+lg*4];
        #pragma unroll
        for (int sub=0; sub<4; sub++)
          racc[sub][df] = __builtin_amdgcn_mfma_f32_16x16x16f16(paf[sub], bfr, racc[sub][df], 0,0,0);
      }
    }
    if (notlast){
      __syncthreads();
      STORET();
      __syncthreads();
    }
  }

  if (mode==0){
    float lam = softplus_(lmp[0]) + 1e-6f;
    #pragma unroll
    for (int sub=0; sub<4; sub++)
      #pragma unroll
      for (int df=0; df<4; df++)
        #pragma unroll
        for (int rg=0; rg<4; rg++){
          int dd = df*16 + lr_;
          int s = sw + sub*16 + lg*4 + rg;
          size_t gi = ((size_t)bh*S_ + s)*64 + dd;
          resid[gi] = v32[gi] - racc[sub][df][rg] - lam*alpha32[gi];
        }
  } else {
    int b = bh>>4, h = bh&15;
    #pragma unroll
    for (int sub=0; sub<4; sub++)
      #pragma unroll
      for (int df=0; df<4; df++)
        #pragma unroll
        for (int rg=0; rg<4; rg++){
          int dd = df*16 + lr_;
          int s = sw + sub*16 + lg*4 + rg;
          y16[((size_t)(b*S_+s))*1024 + h*64 + dd] = (f16)racc[sub][df][rg];
        }
  }
}

// rbuf[sc,bh,r,d] = sum_{s in chunk sc} lr[h,s,r]*resid[bh,s,d]  (8 chunks of 256)
__global__ __launch_bounds__(256) void reduce_t_k(
    const float* __restrict__ lr32, const float* __restrict__ rsd, float* __restrict__ rbuf)
{
  int dblk = blockIdx.x, bh = blockIdx.y, sc = blockIdx.z, h = bh&15;
  int tid = threadIdx.x, r = tid>>4, dc = tid&15;
  __shared__ __align__(16) float lr_s[128][20];
  __shared__ __align__(16) float rs[128][20];
  float acc = 0.f;
  int row = tid>>1, c8 = (tid&1)*8;
  for (int s0=sc*256; s0<sc*256+256; s0+=128){
    const float* lp = lr32 + ((size_t)h*S_ + s0 + row)*16 + c8;
    const float* rp = rsd  + ((size_t)bh*S_ + s0 + row)*64 + dblk*16 + c8;
    float4 l0 = *(const float4*)lp, l1 = *(const float4*)(lp+4);
    float4 r0 = *(const float4*)rp, r1 = *(const float4*)(rp+4);
    *(float4*)&lr_s[row][c8]   = l0; *(float4*)&lr_s[row][c8+4] = l1;
    *(float4*)&rs[row][c8]     = r0; *(float4*)&rs[row][c8+4]   = r1;
    __syncthreads();
    #pragma unroll 8
    for (int ss=0; ss<128; ss++) acc += lr_s[ss][r]*rs[ss][dc];
    __syncthreads();
  }
  rbuf[((size_t)(sc*32+bh)*16 + r)*64 + dblk*16 + dc] = acc;
}

// alpha = clip(alpha + dp*resid + lr@t), t = sum of 8 rbuf partials
__global__ __launch_bounds__(256) void update_k(
    const float* __restrict__ rsd, const float* __restrict__ alpha_in, int alpha_zero,
    const float* __restrict__ lr32, const float* __restrict__ rbuf,
    const float* __restrict__ dpp,
    float* __restrict__ alpha_out, f16* __restrict__ alphaT)
{
  int sblk = blockIdx.x, bh = blockIdx.y, h = bh&15, s0 = sblk*64;
  int tid = threadIdx.x;
  __shared__ __align__(16) float tb_s[16][64];
  __shared__ __align__(16) float lr_s[64][20];
  __shared__ float dp_s[64];
  __shared__ __align__(16) f16 at_s[64][72];
  {
    float4 t4 = {0.f,0.f,0.f,0.f};
    #pragma unroll
    for (int sc=0; sc<8; sc++){
      float4 p4 = *(const float4*)(rbuf + (size_t)(sc*32+bh)*1024 + tid*4);
      t4.x += p4.x; t4.y += p4.y; t4.z += p4.z; t4.w += p4.w;
    }
    *(float4*)&((float*)tb_s)[tid*4] = t4;
    int row = tid>>2, c4 = (tid&3)*4;
    float4 l4 = *(const float4*)(lr32 + ((size_t)h*S_ + s0 + row)*16 + c4);
    *(float4*)&lr_s[row][c4] = l4;
    if (tid < 64) dp_s[tid] = dpp[(size_t)bh*S_ + s0 + tid];
  }
  __syncthreads();
  #pragma unroll
  for (int i=0;i<16;i++){
    int idx = i*256 + tid;
    int sl = idx>>6, dd = idx&63;
    size_t gi = ((size_t)bh*S_ + s0 + sl)*64 + dd;
    float rv = rsd[gi];
    float av = alpha_zero ? 0.f : alpha_in[gi];
    float acc = av + dp_s[sl]*rv;
    #pragma unroll
    for (int rr=0; rr<16; rr++) acc += lr_s[sl][rr]*tb_s[rr][dd];
    acc = fminf(fmaxf(acc, -10.f), 10.f);
    alpha_out[gi] = acc;
    at_s[dd][sl] = (f16)acc;
  }
  __syncthreads();
  int dd = tid>>2, c16 = (tid&3)*16;
  f16* dst = alphaT + ((size_t)bh*64 + dd)*S_ + s0 + c16;
  *(f16x8*)dst     = *(const f16x8*)&at_s[dd][c16];
  *(f16x8*)(dst+8) = *(const f16x8*)&at_s[dd][c16+8];
}

// ---------------------------------------------------------------------------
extern "C" void kernel_launch(void* const* d_in, const int* in_sizes, int n_in,
                              void* d_out, int out_size, void* d_ws, size_t ws_size,
                              hipStream_t stream)
{
  const float* x   = (const float*)d_in[0];
  const float* wq  = (const float*)d_in[1];
  const float* wk  = (const float*)d_in[2];
  const float* wv  = (const float*)d_in[3];
  const float* wo  = (const float*)d_in[4];
  const float* bwp = (const float*)d_in[5];
  const float* dsp = (const float*)d_in[6];
  const float* rgp = (const float*)d_in[7];
  const float* pos = (const float*)d_in[8];
  const float* hpj = (const float*)d_in[9];
  const float* lmp = (const float*)d_in[10];
  float* outp = (float*)d_out;

  char* base = (char*)d_ws;
  size_t off = 0;
  auto carve = [&](size_t bytes)->char* {
    char* p = base + off; off += (bytes + 255) & ~(size_t)255; return p;
  };
  f16*   x16    = (f16*)  carve((size_t)4096*1024*2);     // 8 MB
  f16*   wqkv16 = (f16*)  carve((size_t)3072*1024*2);     // 6 MB
  f16*   wo16   = (f16*)  carve((size_t)1024*1024*2);     // 2 MB
  f16*   q16    = (f16*)  carve((size_t)BH_*S_*64*2);     // 8 MB
  f16*   k16    = (f16*)  carve((size_t)BH_*S_*64*2);     // 8 MB
  float* v32    = (float*)carve((size_t)BH_*S_*64*4);     // 16 MB
  float* alpha  = (float*)carve((size_t)BH_*S_*64*4);     // 16 MB
  f16*   alphaT = (f16*)  carve((size_t)BH_*64*S_*2);     // 8 MB
  float* resid  = (float*)carve((size_t)BH_*S_*64*4);     // 16 MB
  f16*   y16    = (f16*)  carve((size_t)4096*1024*2);     // 8 MB
  float* bs     = (float*)carve((size_t)BH_*S_*4);
  float* ct     = (float*)carve((size_t)BH_*S_*4);
  float* dp     = (float*)carve((size_t)BH_*S_*4);
  float* lr32   = (float*)carve((size_t)H_*S_*16*4);      // 2 MB
  float* rbuf   = (float*)carve((size_t)8*BH_*16*64*4);   // 2 MB

  // f32 -> f16 conversions
  cvt_k<<<2048,256,0,stream>>>(x,  x16,               4096*1024/8);
  cvt_k<<< 512,256,0,stream>>>(wq, wqkv16,            1024*1024/8);
  cvt_k<<< 512,256,0,stream>>>(wk, wqkv16+1024*1024,  1024*1024/8);
  cvt_k<<< 512,256,0,stream>>>(wv, wqkv16+2*1024*1024,1024*1024/8);
  cvt_k<<< 512,256,0,stream>>>(wo, wo16,              1024*1024/8);
  // fused QKV projection
  gemm16_k<<<dim3(24,32),256,0,stream>>>(x16, wqkv16, q16, k16, v32, nullptr, 0);
  stats_k<<<256,256,0,stream>>>(q16,k16,bwp,dsp,rgp,bs,ct,dp);
  lr_k<<<2048,256,0,stream>>>(pos,hpj,lr32);
  // iteration 1: alpha=0 -> residual = v
  reduce_t_k<<<dim3(4,32,8),256,0,stream>>>(lr32, v32, rbuf);
  update_k<<<dim3(32,32),256,0,stream>>>(v32, alpha, 1, lr32, rbuf, dp, alpha, alphaT);
  // iterations 2..8
  for (int it=1; it<8; ++it){
    apply_k<<<256,256,0,stream>>>(q16,k16,alphaT,bs,ct,v32,alpha,bwp,lmp,resid,nullptr,0);
    reduce_t_k<<<dim3(4,32,8),256,0,stream>>>(lr32, resid, rbuf);
    update_k<<<dim3(32,32),256,0,stream>>>(resid, alpha, 0, lr32, rbuf, dp, alpha, alphaT);
  }
  // final: out = K @ alpha, then output projection
  apply_k<<<256,256,0,stream>>>(q16,k16,alphaT,bs,ct,v32,alpha,bwp,lmp,resid,y16,1);
  gemm16_k<<<dim3(8,32),256,0,stream>>>(y16, wo16, nullptr, nullptr, nullptr, outp, 1);
}

// Round 6
// 802.864 us; speedup vs baseline: 1.6282x; 1.2608x over previous
//
#include <hip/hip_runtime.h>

typedef _Float16 f16;
typedef _Float16 f16x2 __attribute__((ext_vector_type(2)));
typedef _Float16 f16x4 __attribute__((ext_vector_type(4)));
typedef _Float16 f16x8 __attribute__((ext_vector_type(8)));
typedef float f32x4 __attribute__((ext_vector_type(4)));

#define DEVI static __device__ __forceinline__

constexpr int S_  = 2048;
constexpr int H_  = 16;
constexpr int BH_ = 32;   // B*H

DEVI float softplus_(float x){ return logf(1.0f + expf(x)); }
DEVI float exp2_(float x){ return __builtin_amdgcn_exp2f(x); }

DEVI f16x2 cvt2(float a, float b){
  return __builtin_bit_cast(f16x2, __builtin_amdgcn_cvt_pkrtz(a, b));
}

DEVI f16x8 pack8(float4 a, float4 b){
  f16x2 p0 = cvt2(a.x, a.y);
  f16x2 p1 = cvt2(a.z, a.w);
  f16x2 p2 = cvt2(b.x, b.y);
  f16x2 p3 = cvt2(b.z, b.w);
  f16x8 o;
  o[0]=p0[0]; o[1]=p0[1]; o[2]=p1[0]; o[3]=p1[1];
  o[4]=p2[0]; o[5]=p2[1]; o[6]=p3[0]; o[7]=p3[1];
  return o;
}

DEVI void g2l16(const f16* g, f16* l){
  __builtin_amdgcn_global_load_lds(
      (const __attribute__((address_space(1))) void*)(g),
      (__attribute__((address_space(3))) void*)(l), 16, 0, 0);
}

// f32 -> f16 convert, 8 elems/thread
__global__ __launch_bounds__(256) void cvt_k(
    const float* __restrict__ src, f16* __restrict__ dst, int n8)
{
  int i = blockIdx.x*256 + threadIdx.x;
  if (i < n8){
    const float* s = src + (size_t)i*8;
    float4 a = *(const float4*)s, b = *(const float4*)(s+4);
    *(f16x8*)(dst + (size_t)i*8) = pack8(a,b);
  }
}

// ---------------------------------------------------------------------------
// f16 GEMM, m97-style: C[M,N] = A[M,1024] * W[N,1024]^T
// ---------------------------------------------------------------------------
__global__ __launch_bounds__(256) void gemm16_k(
    const f16* __restrict__ A, const f16* __restrict__ W,
    f16* __restrict__ q16, f16* __restrict__ k16, float* __restrict__ v32,
    float* __restrict__ o32f, int mode)
{
  constexpr int K = 1024;
  int n0 = blockIdx.x*128, m0 = blockIdx.y*128;
  int tid = threadIdx.x, wave = tid>>6, lane = tid&63, lr_ = lane&15, lg = lane>>4;
  int wm = (wave&1)*64, wn = (wave>>1)*64;
  __shared__ __align__(16) f16 As[128*32];
  __shared__ __align__(16) f16 Ws[128*32];
  f32x4 acc[4][4];
  #pragma unroll
  for (int a=0;a<4;a++)
    #pragma unroll
    for (int b=0;b<4;b++) acc[a][b] = (f32x4){0.f,0.f,0.f,0.f};

  int r1 = tid>>2,        o1 = (tid&3)*8;
  int r2 = (tid+256)>>2,  o2 = ((tid+256)&3)*8;
  const f16* a1 = A + (size_t)(m0+r1)*K + o1;
  const f16* a2 = A + (size_t)(m0+r2)*K + o2;
  const f16* w1 = W + (size_t)(n0+r1)*K + o1;
  const f16* w2 = W + (size_t)(n0+r2)*K + o2;
  f16* la1 = &As[tid*8];  f16* la2 = &As[(tid+256)*8];
  f16* lw1 = &Ws[tid*8];  f16* lw2 = &Ws[(tid+256)*8];

  for (int kt=0; kt<K; kt+=32){
    g2l16(a1 + kt, la1);
    g2l16(a2 + kt, la2);
    g2l16(w1 + kt, lw1);
    g2l16(w2 + kt, lw2);
    __syncthreads();
    f16x8 af[4], bf[4];
    #pragma unroll
    for (int mf=0;mf<4;mf++) af[mf] = *(const f16x8*)&As[(wm+mf*16+lr_)*32 + lg*8];
    #pragma unroll
    for (int nf=0;nf<4;nf++) bf[nf] = *(const f16x8*)&Ws[(wn+nf*16+lr_)*32 + lg*8];
    #pragma unroll
    for (int mf=0;mf<4;mf++)
      #pragma unroll
      for (int nf=0;nf<4;nf++)
        acc[mf][nf] = __builtin_amdgcn_mfma_f32_16x16x32_f16(af[mf], bf[nf], acc[mf][nf], 0,0,0);
    __syncthreads();
  }
  #pragma unroll
  for (int mf=0;mf<4;mf++)
    #pragma unroll
    for (int nf=0;nf<4;nf++)
      #pragma unroll
      for (int rg=0;rg<4;rg++){
        int grow = m0+wm+mf*16+lg*4+rg;
        int gcol = n0+wn+nf*16+lr_;
        float vv = acc[mf][nf][rg];
        if (mode==0){
          int mat = gcol>>10, col = gcol&1023;
          int b = grow>>11, s = grow&2047, hh = col>>6, d2 = col&63;
          size_t gi = (((size_t)(b*16+hh))*S_ + s)*64 + d2;
          if (mat==0)      q16[gi] = (f16)vv;
          else if (mat==1) k16[gi] = (f16)vv;
          else             v32[gi] = vv;
        } else {
          o32f[(size_t)grow*1024 + gcol] = vv;
        }
      }
}

// ---------------------------------------------------------------------------
__global__ __launch_bounds__(256) void stats_k(
    const f16* __restrict__ q16, const f16* __restrict__ k16,
    const float* __restrict__ bwp, const float* __restrict__ dsp, const float* __restrict__ rgp,
    float* __restrict__ bs, float* __restrict__ ct, float* __restrict__ dp)
{
  int g = blockIdx.x*256 + threadIdx.x;
  int h = (g>>11)&15;
  float bw = softplus_(bwp[0]) + 1e-6f;
  float c2 = 1.f/(2.f*bw*bw*0.6931471805599453f);
  const f16* qr = q16 + (size_t)g*64;
  const f16* kr = k16 + (size_t)g*64;
  float qsq=0.f, ksq=0.f, qk=0.f;
  #pragma unroll
  for (int c=0;c<8;c++){
    f16x8 qv = *(const f16x8*)(qr + c*8);
    f16x8 kv = *(const f16x8*)(kr + c*8);
    #pragma unroll
    for (int j=0;j<8;j++){
      float a = (float)qv[j], b = (float)kv[j];
      qsq += a*a; ksq += b*b; qk += a*b;
    }
  }
  bs[g] = -qsq*c2;
  ct[g] = -ksq*c2;
  float dist = fmaxf(qsq + ksq - 2.f*qk, 0.f);
  float kd = exp2_(-dist*c2);
  dp[g] = softplus_(kd)*dsp[h] + rgp[0];
}

// lr[h,s,p] = sum_r pos[s,r]*hp[h,r,p]
__global__ __launch_bounds__(256) void lr_k(
    const float* __restrict__ pos, const float* __restrict__ hpj, float* __restrict__ lr32)
{
  int g = blockIdx.x*256 + threadIdx.x;
  int p = g&15, s = (g>>4)&2047, h = g>>15;
  float acc = 0.f;
  #pragma unroll
  for (int r=0;r<16;r++) acc += pos[s*16+r]*hpj[(h*16+r)*16+p];
  lr32[g] = acc;
}

// ---------------------------------------------------------------------------
// Fused apply v4: R = K @ alpha. 512 threads (8 waves x 32 s-rows = 256 rows),
// grid 256 (1 block/CU, 2 waves/SIMD), LDS double-buffered, 1 barrier/tile.
// mode 0: resid = v - R - lam*alpha      mode 1: y16[b,s,h*64+d] = R
// ---------------------------------------------------------------------------
__global__ __launch_bounds__(512,1) void apply_k(
    const f16* __restrict__ q16, const f16* __restrict__ k16,
    const f16* __restrict__ alphaT,
    const float* __restrict__ bs, const float* __restrict__ ct,
    const float* __restrict__ v32, const float* __restrict__ alpha32,
    const float* __restrict__ bwp, const float* __restrict__ lmp,
    float* __restrict__ resid, f16* __restrict__ y16,
    int mode)
{
  // grid = 256: 4 bh per XCD -> k16+alphaT slices (2MB) L2-resident
  int id = blockIdx.x;
  int bh = ((id&7)<<2) | ((id>>3)&3);
  int s0 = (id>>5)*256;

  float bw = softplus_(bwp[0]) + 1e-6f;
  float c2 = 1.f/(2.f*bw*bw*0.6931471805599453f);
  float acoef = 2.f*c2;

  int tid = threadIdx.x, wave = tid>>6, lane = tid&63, lr_ = lane&15, lg = lane>>4;
  int sw = s0 + wave*32;                   // this wave's 32 s-rows (2 x 16)

  f16x8 q0[2], q1[2]; float bsv[2];
  #pragma unroll
  for (int sub=0; sub<2; sub++){
    const f16* qr = q16 + ((size_t)bh*S_ + sw + sub*16 + lr_)*64;
    q0[sub] = *(const f16x8*)(qr + lg*8);
    q1[sub] = *(const f16x8*)(qr + 32 + lg*8);
    bsv[sub] = bs[bh*S_ + sw + sub*16 + lr_];
  }

  __shared__ __align__(16) f16 ks[2][64][72];
  __shared__ __align__(16) f16 at[2][64][72];
  __shared__ __align__(16) float cts[2][64];

  f32x4 racc[2][4];
  #pragma unroll
  for (int sub=0;sub<2;sub++)
    #pragma unroll
    for (int df=0;df<4;df++) racc[sub][df] = (f32x4){0.f,0.f,0.f,0.f};

  // staging: 512 threads x one 16B chunk each of ks and at per tile
  int srow = tid>>3, scol = (tid&7)*8;
  const f16* kg = k16    + ((size_t)bh*S_ + srow)*64 + scol;   // + t0*64
  const f16* ag = alphaT + ((size_t)bh*64 + srow)*S_ + scol;   // + t0
  const float* ctb = ct + (size_t)bh*S_;
  int lct = tid&63;

  f16x8 kv, av; float ctp;
  auto LOADT = [&](int t0){
    kv  = *(const f16x8*)(kg + (size_t)t0*64);
    av  = *(const f16x8*)(ag + t0);
    ctp = ctb[t0 + lct];
  };
  auto STORET = [&](int b){
    *(f16x8*)&ks[b][srow][scol] = kv;
    *(f16x8*)&at[b][srow][scol] = av;
    cts[b][lct] = ctp;                     // redundant across waves, benign
  };

  LOADT(0);
  STORET(0);
  LOADT(64);
  __syncthreads();

  for (int t0=0; t0<S_; t0+=64){
    int b = (t0>>6)&1;
    if (t0+64 < S_)  STORET(b^1);          // regs from LOADT(t0+64), vmcnt covered
    if (t0+128 < S_) LOADT(t0+128);        // prefetch 2 tiles ahead
    #pragma unroll
    for (int tf=0; tf<4; tf++){
      f16x8 ka0 = *(const f16x8*)&ks[b][tf*16+lr_][lg*8];
      f16x8 ka1 = *(const f16x8*)&ks[b][tf*16+lr_][32+lg*8];
      f32x4 sacc[2];
      #pragma unroll
      for (int sub=0; sub<2; sub++){
        sacc[sub] = (f32x4){0.f,0.f,0.f,0.f};
        sacc[sub] = __builtin_amdgcn_mfma_f32_16x16x32_f16(ka0, q0[sub], sacc[sub], 0,0,0);
        sacc[sub] = __builtin_amdgcn_mfma_f32_16x16x32_f16(ka1, q1[sub], sacc[sub], 0,0,0);
      }
      f32x4 ctv = *(const f32x4*)&cts[b][tf*16 + lg*4];
      f16x4 paf[2];
      #pragma unroll
      for (int sub=0; sub<2; sub++){
        float p0 = exp2_(fminf(fmaf(acoef, sacc[sub][0], bsv[sub] + ctv[0]), 0.f));
        float p1 = exp2_(fminf(fmaf(acoef, sacc[sub][1], bsv[sub] + ctv[1]), 0.f));
        float p2 = exp2_(fminf(fmaf(acoef, sacc[sub][2], bsv[sub] + ctv[2]), 0.f));
        float p3 = exp2_(fminf(fmaf(acoef, sacc[sub][3], bsv[sub] + ctv[3]), 0.f));
        f16x2 lo = cvt2(p0,p1), hi = cvt2(p2,p3);
        paf[sub][0]=lo[0]; paf[sub][1]=lo[1]; paf[sub][2]=hi[0]; paf[sub][3]=hi[1];
      }
      #pragma unroll
      for (int df=0; df<4; df++){
        f16x4 bfr = *(const f16x4*)&at[b][df*16+lr_][tf*16+lg*4];
        #pragma unroll
        for (int sub=0; sub<2; sub++)
          racc[sub][df] = __builtin_amdgcn_mfma_f32_16x16x16f16(paf[sub], bfr, racc[sub][df], 0,0,0);
      }
    }
    __syncthreads();
  }

  if (mode==0){
    float lam = softplus_(lmp[0]) + 1e-6f;
    #pragma unroll
    for (int sub=0; sub<2; sub++)
      #pragma unroll
      for (int df=0; df<4; df++)
        #pragma unroll
        for (int rg=0; rg<4; rg++){
          int dd = df*16 + lr_;
          int s = sw + sub*16 + lg*4 + rg;
          size_t gi = ((size_t)bh*S_ + s)*64 + dd;
          resid[gi] = v32[gi] - racc[sub][df][rg] - lam*alpha32[gi];
        }
  } else {
    int b2 = bh>>4, h = bh&15;
    #pragma unroll
    for (int sub=0; sub<2; sub++)
      #pragma unroll
      for (int df=0; df<4; df++)
        #pragma unroll
        for (int rg=0; rg<4; rg++){
          int dd = df*16 + lr_;
          int s = sw + sub*16 + lg*4 + rg;
          y16[((size_t)(b2*S_+s))*1024 + h*64 + dd] = (f16)racc[sub][df][rg];
        }
  }
}

// rbuf[sc,bh,r,d] = sum_{s in chunk sc} lr[h,s,r]*resid[bh,s,d]  (8 chunks of 256)
__global__ __launch_bounds__(256) void reduce_t_k(
    const float* __restrict__ lr32, const float* __restrict__ rsd, float* __restrict__ rbuf)
{
  int dblk = blockIdx.x, bh = blockIdx.y, sc = blockIdx.z, h = bh&15;
  int tid = threadIdx.x, r = tid>>4, dc = tid&15;
  __shared__ __align__(16) float lr_s[128][20];
  __shared__ __align__(16) float rs[128][20];
  float acc = 0.f;
  int row = tid>>1, c8 = (tid&1)*8;
  for (int s0=sc*256; s0<sc*256+256; s0+=128){
    const float* lp = lr32 + ((size_t)h*S_ + s0 + row)*16 + c8;
    const float* rp = rsd  + ((size_t)bh*S_ + s0 + row)*64 + dblk*16 + c8;
    float4 l0 = *(const float4*)lp, l1 = *(const float4*)(lp+4);
    float4 r0 = *(const float4*)rp, r1 = *(const float4*)(rp+4);
    *(float4*)&lr_s[row][c8]   = l0; *(float4*)&lr_s[row][c8+4] = l1;
    *(float4*)&rs[row][c8]     = r0; *(float4*)&rs[row][c8+4]   = r1;
    __syncthreads();
    #pragma unroll 8
    for (int ss=0; ss<128; ss++) acc += lr_s[ss][r]*rs[ss][dc];
    __syncthreads();
  }
  rbuf[((size_t)(sc*32+bh)*16 + r)*64 + dblk*16 + dc] = acc;
}

// alpha = clip(alpha + dp*resid + lr@t), t = sum of 8 rbuf partials
__global__ __launch_bounds__(256) void update_k(
    const float* __restrict__ rsd, const float* __restrict__ alpha_in, int alpha_zero,
    const float* __restrict__ lr32, const float* __restrict__ rbuf,
    const float* __restrict__ dpp,
    float* __restrict__ alpha_out, f16* __restrict__ alphaT)
{
  int sblk = blockIdx.x, bh = blockIdx.y, h = bh&15, s0 = sblk*64;
  int tid = threadIdx.x;
  __shared__ __align__(16) float tb_s[16][64];
  __shared__ __align__(16) float lr_s[64][20];
  __shared__ float dp_s[64];
  __shared__ __align__(16) f16 at_s[64][72];
  {
    float4 t4 = {0.f,0.f,0.f,0.f};
    #pragma unroll
    for (int sc=0; sc<8; sc++){
      float4 p4 = *(const float4*)(rbuf + (size_t)(sc*32+bh)*1024 + tid*4);
      t4.x += p4.x; t4.y += p4.y; t4.z += p4.z; t4.w += p4.w;
    }
    *(float4*)&((float*)tb_s)[tid*4] = t4;
    int row = tid>>2, c4 = (tid&3)*4;
    float4 l4 = *(const float4*)(lr32 + ((size_t)h*S_ + s0 + row)*16 + c4);
    *(float4*)&lr_s[row][c4] = l4;
    if (tid < 64) dp_s[tid] = dpp[(size_t)bh*S_ + s0 + tid];
  }
  __syncthreads();
  #pragma unroll
  for (int i=0;i<16;i++){
    int idx = i*256 + tid;
    int sl = idx>>6, dd = idx&63;
    size_t gi = ((size_t)bh*S_ + s0 + sl)*64 + dd;
    float rv = rsd[gi];
    float av = alpha_zero ? 0.f : alpha_in[gi];
    float acc = av + dp_s[sl]*rv;
    #pragma unroll
    for (int rr=0; rr<16; rr++) acc += lr_s[sl][rr]*tb_s[rr][dd];
    acc = fminf(fmaxf(acc, -10.f), 10.f);
    alpha_out[gi] = acc;
    at_s[dd][sl] = (f16)acc;
  }
  __syncthreads();
  int dd = tid>>2, c16 = (tid&3)*16;
  f16* dst = alphaT + ((size_t)bh*64 + dd)*S_ + s0 + c16;
  *(f16x8*)dst     = *(const f16x8*)&at_s[dd][c16];
  *(f16x8*)(dst+8) = *(const f16x8*)&at_s[dd][c16+8];
}

// ---------------------------------------------------------------------------
extern "C" void kernel_launch(void* const* d_in, const int* in_sizes, int n_in,
                              void* d_out, int out_size, void* d_ws, size_t ws_size,
                              hipStream_t stream)
{
  const float* x   = (const float*)d_in[0];
  const float* wq  = (const float*)d_in[1];
  const float* wk  = (const float*)d_in[2];
  const float* wv  = (const float*)d_in[3];
  const float* wo  = (const float*)d_in[4];
  const float* bwp = (const float*)d_in[5];
  const float* dsp = (const float*)d_in[6];
  const float* rgp = (const float*)d_in[7];
  const float* pos = (const float*)d_in[8];
  const float* hpj = (const float*)d_in[9];
  const float* lmp = (const float*)d_in[10];
  float* outp = (float*)d_out;

  char* base = (char*)d_ws;
  size_t off = 0;
  auto carve = [&](size_t bytes)->char* {
    char* p = base + off; off += (bytes + 255) & ~(size_t)255; return p;
  };
  f16*   x16    = (f16*)  carve((size_t)4096*1024*2);     // 8 MB
  f16*   wqkv16 = (f16*)  carve((size_t)3072*1024*2);     // 6 MB
  f16*   wo16   = (f16*)  carve((size_t)1024*1024*2);     // 2 MB
  f16*   q16    = (f16*)  carve((size_t)BH_*S_*64*2);     // 8 MB
  f16*   k16    = (f16*)  carve((size_t)BH_*S_*64*2);     // 8 MB
  float* v32    = (float*)carve((size_t)BH_*S_*64*4);     // 16 MB
  float* alpha  = (float*)carve((size_t)BH_*S_*64*4);     // 16 MB
  f16*   alphaT = (f16*)  carve((size_t)BH_*64*S_*2);     // 8 MB
  float* resid  = (float*)carve((size_t)BH_*S_*64*4);     // 16 MB
  f16*   y16    = (f16*)  carve((size_t)4096*1024*2);     // 8 MB
  float* bs     = (float*)carve((size_t)BH_*S_*4);
  float* ct     = (float*)carve((size_t)BH_*S_*4);
  float* dp     = (float*)carve((size_t)BH_*S_*4);
  float* lr32   = (float*)carve((size_t)H_*S_*16*4);      // 2 MB
  float* rbuf   = (float*)carve((size_t)8*BH_*16*64*4);   // 2 MB

  // f32 -> f16 conversions
  cvt_k<<<2048,256,0,stream>>>(x,  x16,               4096*1024/8);
  cvt_k<<< 512,256,0,stream>>>(wq, wqkv16,            1024*1024/8);
  cvt_k<<< 512,256,0,stream>>>(wk, wqkv16+1024*1024,  1024*1024/8);
  cvt_k<<< 512,256,0,stream>>>(wv, wqkv16+2*1024*1024,1024*1024/8);
  cvt_k<<< 512,256,0,stream>>>(wo, wo16,              1024*1024/8);
  // fused QKV projection
  gemm16_k<<<dim3(24,32),256,0,stream>>>(x16, wqkv16, q16, k16, v32, nullptr, 0);
  stats_k<<<256,256,0,stream>>>(q16,k16,bwp,dsp,rgp,bs,ct,dp);
  lr_k<<<2048,256,0,stream>>>(pos,hpj,lr32);
  // iteration 1: alpha=0 -> residual = v
  reduce_t_k<<<dim3(4,32,8),256,0,stream>>>(lr32, v32, rbuf);
  update_k<<<dim3(32,32),256,0,stream>>>(v32, alpha, 1, lr32, rbuf, dp, alpha, alphaT);
  // iterations 2..8
  for (int it=1; it<8; ++it){
    apply_k<<<256,512,0,stream>>>(q16,k16,alphaT,bs,ct,v32,alpha,bwp,lmp,resid,nullptr,0);
    reduce_t_k<<<dim3(4,32,8),256,0,stream>>>(lr32, resid, rbuf);
    update_k<<<dim3(32,32),256,0,stream>>>(resid, alpha, 0, lr32, rbuf, dp, alpha, alphaT);
  }
  // final: out = K @ alpha, then output projection
  apply_k<<<256,512,0,stream>>>(q16,k16,alphaT,bs,ct,v32,alpha,bwp,lmp,resid,y16,1);
  gemm16_k<<<dim3(8,32),256,0,stream>>>(y16, wo16, nullptr, nullptr, nullptr, outp, 1);
}